// Round 5
// baseline (472.778 us; speedup 1.0000x reference)
//
#include <hip/hip_runtime.h>

#define N_NODES 50000
#define N_EDGES 800000
#define D 128
#define NB 16       // nodes per GEMM block (50000 = 3125 * 16, no tail)
#define NREP 8      // histogram/cursor replicas
#define SCAN_B 256
#define N_SBLK ((N_NODES + SCAN_B - 1) / SCAN_B)  // 196
#define EDGE_BLOCKS ((N_EDGES + 255) / 256)       // 3125

// ---------------- degree histograms, 8-way replicated ----------------
__global__ void deg_kernel(const int* __restrict__ src, const int* __restrict__ dst,
                           int* __restrict__ cnt8_src, int* __restrict__ cnt8_dst, int nE) {
    int e = blockIdx.x * blockDim.x + threadIdx.x;
    int r = blockIdx.x & (NREP - 1);
    if (e < nE) {
        atomicAdd(&cnt8_src[r * N_NODES + src[e]], 1);
        atomicAdd(&cnt8_dst[r * N_NODES + dst[e]], 1);
    }
}

// ---------------- hierarchical scan, step 1: per-block sums of Σ_r cnt8_dst ----------------
__global__ void scan_sum_kernel(const int* __restrict__ cnt8, int* __restrict__ blkSum, int n) {
    __shared__ int tmp[SCAN_B];
    int t = threadIdx.x;
    int i = blockIdx.x * SCAN_B + t;
    int v = 0;
    if (i < n) {
#pragma unroll
        for (int r = 0; r < NREP; r++) v += cnt8[r * N_NODES + i];
    }
    tmp[t] = v;
    __syncthreads();
    for (int d = 128; d > 0; d >>= 1) {
        if (t < d) tmp[t] += tmp[t + d];
        __syncthreads();
    }
    if (t == 0) blkSum[blockIdx.x] = tmp[0];
}

// ---------------- hierarchical scan, step 2: exclusive offsets ----------------
__global__ void scan_off_kernel(const int* __restrict__ cnt8, const int* __restrict__ blkSum,
                                int* __restrict__ off, int n, int nBlk) {
    __shared__ int bs[SCAN_B];
    __shared__ int tmp[SCAN_B];
    int t = threadIdx.x;
    bs[t] = (t < nBlk) ? blkSum[t] : 0;
    __syncthreads();
    for (int d = 1; d < SCAN_B; d <<= 1) {
        int a = (t >= d) ? bs[t - d] : 0;
        __syncthreads();
        bs[t] += a;
        __syncthreads();
    }
    int base = (blockIdx.x > 0) ? bs[blockIdx.x - 1] : 0;
    int i = blockIdx.x * SCAN_B + t;
    int v = 0;
    if (i < n) {
#pragma unroll
        for (int r = 0; r < NREP; r++) v += cnt8[r * N_NODES + i];
    }
    tmp[t] = v;
    __syncthreads();
    for (int d = 1; d < SCAN_B; d <<= 1) {
        int a = (t >= d) ? tmp[t - d] : 0;
        __syncthreads();
        tmp[t] += a;
        __syncthreads();
    }
    if (i < n) off[i] = base + tmp[t] - v;   // exclusive prefix
    if (i == n - 1) off[n] = base + tmp[t];  // total
}

// ---------------- fused: rs arrays, per-replica cursor init, xs = x * rs_out ----------------
__global__ void prescale_kernel(const float4* __restrict__ x, const int* __restrict__ cnt8_src,
                                const int* __restrict__ cnt8_dst, const int* __restrict__ off,
                                float* __restrict__ rs_out, float* __restrict__ rs_in,
                                int* __restrict__ cursor8, float4* __restrict__ xs, int nN) {
    int node = blockIdx.x * 8 + (threadIdx.x >> 5);
    int c = threadIdx.x & 31;
    if (node >= nN) return;
    float rs_o = 0.0f;
    if (c == 0) {
        int ssum = 0, dsum = 0;
        int base = off[node];
#pragma unroll
        for (int r = 0; r < NREP; r++) {
            ssum += cnt8_src[r * N_NODES + node];
            int d = cnt8_dst[r * N_NODES + node];
            cursor8[r * N_NODES + node] = base;
            base += d;
            dsum += d;
        }
        rs_o = rsqrtf(fmaxf((float)ssum, 1.0f));
        rs_out[node] = rs_o;
        rs_in[node] = rsqrtf(fmaxf((float)dsum, 1.0f));
    }
    // broadcast rs_o from the node's lane 0 within the wave (lanes 0 and 32)
    rs_o = __shfl(rs_o, threadIdx.x & 32);
    float4 v = x[(size_t)node * 32 + c];
    v.x *= rs_o; v.y *= rs_o; v.z *= rs_o; v.w *= rs_o;
    xs[(size_t)node * 32 + c] = v;
}

// ---------------- scatter edges into CSR (replica cursors, same mapping as deg) ----------------
__global__ void scatter_kernel(const int* __restrict__ src, const int* __restrict__ dst,
                               int* __restrict__ cursor8, int* __restrict__ csr_src, int nE) {
    int e = blockIdx.x * blockDim.x + threadIdx.x;
    int r = blockIdx.x & (NREP - 1);
    if (e < nE) {
        int pos = atomicAdd(&cursor8[r * N_NODES + dst[e]], 1);
        csr_src[pos] = src[e];
    }
}

// ---------------- gather aggregation (pure row-sum, 4-way unrolled) ----------------
__global__ void gather_kernel(const float4* __restrict__ xin, const int* __restrict__ off,
                              const int* __restrict__ csr_src, float4* __restrict__ msg, int nN) {
    int node = blockIdx.x * 8 + (threadIdx.x >> 5);
    int c = threadIdx.x & 31;
    if (node >= nN) return;
    int beg = off[node], end = off[node + 1];
    float4 a0 = make_float4(0.f, 0.f, 0.f, 0.f);
    float4 a1 = make_float4(0.f, 0.f, 0.f, 0.f);
    float4 a2 = make_float4(0.f, 0.f, 0.f, 0.f);
    float4 a3 = make_float4(0.f, 0.f, 0.f, 0.f);
    int e = beg;
    for (; e + 3 < end; e += 4) {
        int s0 = csr_src[e];
        int s1 = csr_src[e + 1];
        int s2 = csr_src[e + 2];
        int s3 = csr_src[e + 3];
        float4 v0 = xin[(size_t)s0 * 32 + c];
        float4 v1 = xin[(size_t)s1 * 32 + c];
        float4 v2 = xin[(size_t)s2 * 32 + c];
        float4 v3 = xin[(size_t)s3 * 32 + c];
        a0.x += v0.x; a0.y += v0.y; a0.z += v0.z; a0.w += v0.w;
        a1.x += v1.x; a1.y += v1.y; a1.z += v1.z; a1.w += v1.w;
        a2.x += v2.x; a2.y += v2.y; a2.z += v2.z; a2.w += v2.w;
        a3.x += v3.x; a3.y += v3.y; a3.z += v3.z; a3.w += v3.w;
    }
    for (; e < end; e++) {
        int s0 = csr_src[e];
        float4 v0 = xin[(size_t)s0 * 32 + c];
        a0.x += v0.x; a0.y += v0.y; a0.z += v0.z; a0.w += v0.w;
    }
    a0.x += a1.x + a2.x + a3.x;
    a0.y += a1.y + a2.y + a3.y;
    a0.z += a1.z + a2.z + a3.z;
    a0.w += a1.w + a2.w + a3.w;
    msg[(size_t)node * 32 + c] = a0;
}

// ---------------- per-node dense layer: scalar-B GEMM, no LDS ----------------
// out[node][tid] = f( rs_in[node] * (msg[node][:] @ W[:,tid]) + bias[tid] )
// msg address is wave-uniform -> compiler emits s_load_dwordx4 (scalar path)
template <bool RELU_OUTSCALE>
__global__ void gemm_kernel(const float4* __restrict__ msg4, const float* __restrict__ rs_in,
                            const float* __restrict__ rs_out, const float* __restrict__ W,
                            const float* __restrict__ bias, float* __restrict__ out) {
    int tid = threadIdx.x;  // 0..127 = output column
    int n0 = blockIdx.x * NB;
    float acc[NB];
#pragma unroll
    for (int n = 0; n < NB; n++) acc[n] = 0.0f;
    for (int k4 = 0; k4 < 32; k4++) {
        float w0 = W[(k4 * 4 + 0) * D + tid];
        float w1 = W[(k4 * 4 + 1) * D + tid];
        float w2 = W[(k4 * 4 + 2) * D + tid];
        float w3 = W[(k4 * 4 + 3) * D + tid];
#pragma unroll
        for (int n = 0; n < NB; n++) {
            float4 s4 = msg4[(size_t)(n0 + n) * 32 + k4];  // uniform -> SGPR
            acc[n] += s4.x * w0 + s4.y * w1 + s4.z * w2 + s4.w * w3;
        }
    }
    float bj = bias[tid];
#pragma unroll
    for (int n = 0; n < NB; n++) {
        int node = n0 + n;
        float v = acc[n] * rs_in[node] + bj;
        if (RELU_OUTSCALE) v = fmaxf(v, 0.0f) * rs_out[node];
        out[(size_t)node * D + tid] = v;
    }
}

static inline size_t align16(size_t x) { return (x + 15) & ~(size_t)15; }

extern "C" void kernel_launch(void* const* d_in, const int* in_sizes, int n_in,
                              void* d_out, int out_size, void* d_ws, size_t ws_size,
                              hipStream_t stream) {
    const float* x   = (const float*)d_in[0];
    const int*   src = (const int*)d_in[1];
    const int*   dst = (const int*)d_in[2];
    const float* W1  = (const float*)d_in[3];
    const float* b1  = (const float*)d_in[4];
    const float* W2  = (const float*)d_in[5];
    const float* b2  = (const float*)d_in[6];
    float* out = (float*)d_out;

    // workspace layout. cnt8/cursor8 (4.8 MB) alias the head of msg (25.6 MB):
    // they are dead before gather_kernel writes msg. xs aliases hs.
    char* p = (char*)d_ws;
    float* msg      = (float*)p;
    int*   cnt8_src = (int*)p;                        // NREP * N_NODES
    int*   cnt8_dst = cnt8_src + NREP * N_NODES;      // NREP * N_NODES
    int*   cursor8  = cnt8_dst + NREP * N_NODES;      // NREP * N_NODES
    p += align16((size_t)N_NODES * D * sizeof(float));
    int*   csr_off = (int*)p;   p += align16((N_NODES + 1) * sizeof(int));
    int*   blkSum  = (int*)p;   p += align16(N_SBLK * sizeof(int));
    int*   csr_src = (int*)p;   p += align16((size_t)N_EDGES * sizeof(int));
    float* rs_out  = (float*)p; p += align16(N_NODES * sizeof(float));
    float* rs_in   = (float*)p; p += align16(N_NODES * sizeof(float));
    float* xs      = (float*)p; // aliased with hs
    float* hs      = xs;

    // zero the replicated histograms (adjacent -> one memset)
    hipMemsetAsync(cnt8_src, 0, (size_t)2 * NREP * N_NODES * sizeof(int), stream);

    // replicated histograms
    deg_kernel<<<EDGE_BLOCKS, 256, 0, stream>>>(src, dst, cnt8_src, cnt8_dst, N_EDGES);

    // hierarchical CSR-offset scan of Σ_r cnt8_dst
    scan_sum_kernel<<<N_SBLK, SCAN_B, 0, stream>>>(cnt8_dst, blkSum, N_NODES);
    scan_off_kernel<<<N_SBLK, SCAN_B, 0, stream>>>(cnt8_dst, blkSum, csr_off, N_NODES, N_SBLK);

    // rs arrays + per-replica cursors + xs = x * rs_out
    prescale_kernel<<<(N_NODES + 7) / 8, 256, 0, stream>>>((const float4*)x, cnt8_src, cnt8_dst,
                                                           csr_off, rs_out, rs_in, cursor8,
                                                           (float4*)xs, N_NODES);

    // CSR column build (low-contention replica cursors)
    scatter_kernel<<<EDGE_BLOCKS, 256, 0, stream>>>(src, dst, cursor8, csr_src, N_EDGES);

    // layer 1 aggregation: msg[n] = sum xs[s]
    gather_kernel<<<(N_NODES + 7) / 8, 256, 0, stream>>>((const float4*)xs, csr_off, csr_src,
                                                         (float4*)msg, N_NODES);

    // layer 1 dense: hs = relu(rs_in * (msg @ W1) + b1) * rs_out
    gemm_kernel<true><<<N_NODES / NB, D, 0, stream>>>((const float4*)msg, rs_in, rs_out,
                                                      W1, b1, hs);

    // layer 2 aggregation: msg[n] = sum hs[s]
    gather_kernel<<<(N_NODES + 7) / 8, 256, 0, stream>>>((const float4*)hs, csr_off, csr_src,
                                                         (float4*)msg, N_NODES);

    // layer 2 dense: out = rs_in * (msg @ W2) + b2
    gemm_kernel<false><<<N_NODES / NB, D, 0, stream>>>((const float4*)msg, rs_in, nullptr,
                                                       W2, b2, out);
}

// Round 6
// 412.299 us; speedup vs baseline: 1.1467x; 1.1467x over previous
//
#include <hip/hip_runtime.h>

#define N_NODES 50000
#define N_EDGES 800000
#define D 128
#define NREP 8      // histogram/cursor replicas
#define SCAN_B 256
#define N_SBLK ((N_NODES + SCAN_B - 1) / SCAN_B)  // 196
#define EDGE_BLOCKS ((N_EDGES + 255) / 256)       // 3125
#define GN 64       // nodes per GEMM block

// ---------------- degree histograms, 8-way replicated ----------------
__global__ void deg_kernel(const int* __restrict__ src, const int* __restrict__ dst,
                           int* __restrict__ cnt8_src, int* __restrict__ cnt8_dst, int nE) {
    int e = blockIdx.x * blockDim.x + threadIdx.x;
    int r = blockIdx.x & (NREP - 1);
    if (e < nE) {
        atomicAdd(&cnt8_src[r * N_NODES + src[e]], 1);
        atomicAdd(&cnt8_dst[r * N_NODES + dst[e]], 1);
    }
}

// ---------------- hierarchical scan, step 1: per-block sums of Σ_r cnt8_dst ----------------
__global__ void scan_sum_kernel(const int* __restrict__ cnt8, int* __restrict__ blkSum, int n) {
    __shared__ int tmp[SCAN_B];
    int t = threadIdx.x;
    int i = blockIdx.x * SCAN_B + t;
    int v = 0;
    if (i < n) {
#pragma unroll
        for (int r = 0; r < NREP; r++) v += cnt8[r * N_NODES + i];
    }
    tmp[t] = v;
    __syncthreads();
    for (int d = 128; d > 0; d >>= 1) {
        if (t < d) tmp[t] += tmp[t + d];
        __syncthreads();
    }
    if (t == 0) blkSum[blockIdx.x] = tmp[0];
}

// ---------------- hierarchical scan, step 2: exclusive offsets ----------------
__global__ void scan_off_kernel(const int* __restrict__ cnt8, const int* __restrict__ blkSum,
                                int* __restrict__ off, int n, int nBlk) {
    __shared__ int bs[SCAN_B];
    __shared__ int tmp[SCAN_B];
    int t = threadIdx.x;
    bs[t] = (t < nBlk) ? blkSum[t] : 0;
    __syncthreads();
    for (int d = 1; d < SCAN_B; d <<= 1) {
        int a = (t >= d) ? bs[t - d] : 0;
        __syncthreads();
        bs[t] += a;
        __syncthreads();
    }
    int base = (blockIdx.x > 0) ? bs[blockIdx.x - 1] : 0;
    int i = blockIdx.x * SCAN_B + t;
    int v = 0;
    if (i < n) {
#pragma unroll
        for (int r = 0; r < NREP; r++) v += cnt8[r * N_NODES + i];
    }
    tmp[t] = v;
    __syncthreads();
    for (int d = 1; d < SCAN_B; d <<= 1) {
        int a = (t >= d) ? tmp[t - d] : 0;
        __syncthreads();
        tmp[t] += a;
        __syncthreads();
    }
    if (i < n) off[i] = base + tmp[t] - v;   // exclusive prefix
    if (i == n - 1) off[n] = base + tmp[t];  // total
}

// ---------------- fused: rs arrays, per-replica cursor init, xs = x * rs_out ----------------
__global__ void prescale_kernel(const float4* __restrict__ x, const int* __restrict__ cnt8_src,
                                const int* __restrict__ cnt8_dst, const int* __restrict__ off,
                                float* __restrict__ rs_out, float* __restrict__ rs_in,
                                int* __restrict__ cursor8, float4* __restrict__ xs, int nN) {
    int node = blockIdx.x * 8 + (threadIdx.x >> 5);
    int c = threadIdx.x & 31;
    if (node >= nN) return;
    float rs_o = 0.0f;
    if (c == 0) {
        int ssum = 0, dsum = 0;
        int base = off[node];
#pragma unroll
        for (int r = 0; r < NREP; r++) {
            ssum += cnt8_src[r * N_NODES + node];
            int d = cnt8_dst[r * N_NODES + node];
            cursor8[r * N_NODES + node] = base;
            base += d;
            dsum += d;
        }
        rs_o = rsqrtf(fmaxf((float)ssum, 1.0f));
        rs_out[node] = rs_o;
        rs_in[node] = rsqrtf(fmaxf((float)dsum, 1.0f));
    }
    rs_o = __shfl(rs_o, threadIdx.x & 32);  // broadcast from node's lane 0 / 32
    float4 v = x[(size_t)node * 32 + c];
    v.x *= rs_o; v.y *= rs_o; v.z *= rs_o; v.w *= rs_o;
    xs[(size_t)node * 32 + c] = v;
}

// ---------------- scatter edges into CSR (replica cursors, same mapping as deg) ----------------
__global__ void scatter_kernel(const int* __restrict__ src, const int* __restrict__ dst,
                               int* __restrict__ cursor8, int* __restrict__ csr_src, int nE) {
    int e = blockIdx.x * blockDim.x + threadIdx.x;
    int r = blockIdx.x & (NREP - 1);
    if (e < nE) {
        int pos = atomicAdd(&cursor8[r * N_NODES + dst[e]], 1);
        csr_src[pos] = src[e];
    }
}

// ---------------- gather aggregation (pure row-sum, 4-way unrolled) ----------------
__global__ void gather_kernel(const float4* __restrict__ xin, const int* __restrict__ off,
                              const int* __restrict__ csr_src, float4* __restrict__ msg, int nN) {
    int node = blockIdx.x * 8 + (threadIdx.x >> 5);
    int c = threadIdx.x & 31;
    if (node >= nN) return;
    int beg = off[node], end = off[node + 1];
    float4 a0 = make_float4(0.f, 0.f, 0.f, 0.f);
    float4 a1 = make_float4(0.f, 0.f, 0.f, 0.f);
    float4 a2 = make_float4(0.f, 0.f, 0.f, 0.f);
    float4 a3 = make_float4(0.f, 0.f, 0.f, 0.f);
    int e = beg;
    for (; e + 3 < end; e += 4) {
        int s0 = csr_src[e];
        int s1 = csr_src[e + 1];
        int s2 = csr_src[e + 2];
        int s3 = csr_src[e + 3];
        float4 v0 = xin[(size_t)s0 * 32 + c];
        float4 v1 = xin[(size_t)s1 * 32 + c];
        float4 v2 = xin[(size_t)s2 * 32 + c];
        float4 v3 = xin[(size_t)s3 * 32 + c];
        a0.x += v0.x; a0.y += v0.y; a0.z += v0.z; a0.w += v0.w;
        a1.x += v1.x; a1.y += v1.y; a1.z += v1.z; a1.w += v1.w;
        a2.x += v2.x; a2.y += v2.y; a2.z += v2.z; a2.w += v2.w;
        a3.x += v3.x; a3.y += v3.y; a3.z += v3.z; a3.w += v3.w;
    }
    for (; e < end; e++) {
        int s0 = csr_src[e];
        float4 v0 = xin[(size_t)s0 * 32 + c];
        a0.x += v0.x; a0.y += v0.y; a0.z += v0.z; a0.w += v0.w;
    }
    a0.x += a1.x + a2.x + a3.x;
    a0.y += a1.y + a2.y + a3.y;
    a0.z += a1.z + a2.z + a3.z;
    a0.w += a1.w + a2.w + a3.w;
    msg[(size_t)node * 32 + c] = a0;
}

// ---------------- weight shuffle: WTs[k4*128 + col] = {W[4k4+j][col]} ----------------
__global__ void wshuf_kernel(const float* __restrict__ W1, float4* __restrict__ WTs1,
                             const float* __restrict__ W2, float4* __restrict__ WTs2) {
    int col = threadIdx.x;   // 0..127
    int k4 = blockIdx.x;     // 0..31
    const float* W = blockIdx.y ? W2 : W1;
    float4* WTs = blockIdx.y ? WTs2 : WTs1;
    WTs[k4 * D + col] = make_float4(W[(4 * k4 + 0) * D + col], W[(4 * k4 + 1) * D + col],
                                    W[(4 * k4 + 2) * D + col], W[(4 * k4 + 3) * D + col]);
}

// ---------------- dense layer: 64 nodes x 128 cols per block, 8x4 per thread ----------------
// out[node][col] = f( rs_in[node] * (msg[node][:] @ W[:,col]) + bias[col] )
template <bool RELU_OUTSCALE>
__global__ void gemm_kernel(const float4* __restrict__ msg4, const float* __restrict__ rs_in,
                            const float* __restrict__ rs_out, const float4* __restrict__ WTs,
                            const float* __restrict__ bias, float* __restrict__ out, int nN) {
    __shared__ float4 sA[GN * 32];  // [node][k4], 32 KB
    int tid = threadIdx.x;          // 0..255
    int n0 = blockIdx.x * GN;
    // stage A tile: 2048 float4 by 256 threads, coalesced
#pragma unroll
    for (int it = 0; it < 8; it++) {
        int idx = it * 256 + tid;
        int node = n0 + (idx >> 5);
        int c = idx & 31;
        sA[idx] = (node < nN) ? msg4[(size_t)node * 32 + c] : make_float4(0.f, 0.f, 0.f, 0.f);
    }
    __syncthreads();
    int tx = tid & 31;   // cols tx, tx+32, tx+64, tx+96
    int ty = tid >> 5;   // nodes ty + 8*i
    float acc[8][4];
#pragma unroll
    for (int i = 0; i < 8; i++)
#pragma unroll
        for (int j = 0; j < 4; j++) acc[i][j] = 0.0f;

    for (int k4 = 0; k4 < 32; k4++) {
        float4 w0 = WTs[k4 * D + tx];
        float4 w1 = WTs[k4 * D + tx + 32];
        float4 w2 = WTs[k4 * D + tx + 64];
        float4 w3 = WTs[k4 * D + tx + 96];
#pragma unroll
        for (int i = 0; i < 8; i++) {
            float4 a = sA[(ty + 8 * i) * 32 + k4];
            acc[i][0] += a.x * w0.x + a.y * w0.y + a.z * w0.z + a.w * w0.w;
            acc[i][1] += a.x * w1.x + a.y * w1.y + a.z * w1.z + a.w * w1.w;
            acc[i][2] += a.x * w2.x + a.y * w2.y + a.z * w2.z + a.w * w2.w;
            acc[i][3] += a.x * w3.x + a.y * w3.y + a.z * w3.z + a.w * w3.w;
        }
    }
    float b0 = bias[tx], b1 = bias[tx + 32], b2 = bias[tx + 64], b3 = bias[tx + 96];
#pragma unroll
    for (int i = 0; i < 8; i++) {
        int node = n0 + ty + 8 * i;
        if (node >= nN) continue;
        float ri = rs_in[node];
        float v0 = acc[i][0] * ri + b0;
        float v1 = acc[i][1] * ri + b1;
        float v2 = acc[i][2] * ri + b2;
        float v3 = acc[i][3] * ri + b3;
        if (RELU_OUTSCALE) {
            float ro = rs_out[node];
            v0 = fmaxf(v0, 0.0f) * ro;
            v1 = fmaxf(v1, 0.0f) * ro;
            v2 = fmaxf(v2, 0.0f) * ro;
            v3 = fmaxf(v3, 0.0f) * ro;
        }
        float* o = out + (size_t)node * D;
        o[tx] = v0; o[tx + 32] = v1; o[tx + 64] = v2; o[tx + 96] = v3;
    }
}

static inline size_t align16(size_t x) { return (x + 15) & ~(size_t)15; }

extern "C" void kernel_launch(void* const* d_in, const int* in_sizes, int n_in,
                              void* d_out, int out_size, void* d_ws, size_t ws_size,
                              hipStream_t stream) {
    const float* x   = (const float*)d_in[0];
    const int*   src = (const int*)d_in[1];
    const int*   dst = (const int*)d_in[2];
    const float* W1  = (const float*)d_in[3];
    const float* b1  = (const float*)d_in[4];
    const float* W2  = (const float*)d_in[5];
    const float* b2  = (const float*)d_in[6];
    float* out = (float*)d_out;

    // workspace layout. cnt8/cursor8 (4.8 MB) alias the head of msg (25.6 MB):
    // dead before gather_kernel writes msg. xs aliases hs.
    char* p = (char*)d_ws;
    float* msg      = (float*)p;
    int*   cnt8_src = (int*)p;                        // NREP * N_NODES
    int*   cnt8_dst = cnt8_src + NREP * N_NODES;      // NREP * N_NODES
    int*   cursor8  = cnt8_dst + NREP * N_NODES;      // NREP * N_NODES
    p += align16((size_t)N_NODES * D * sizeof(float));
    int*   csr_off = (int*)p;    p += align16((N_NODES + 1) * sizeof(int));
    int*   blkSum  = (int*)p;    p += align16(N_SBLK * sizeof(int));
    int*   csr_src = (int*)p;    p += align16((size_t)N_EDGES * sizeof(int));
    float* rs_out  = (float*)p;  p += align16(N_NODES * sizeof(float));
    float* rs_in   = (float*)p;  p += align16(N_NODES * sizeof(float));
    float* WTs1    = (float*)p;  p += align16((size_t)D * D * sizeof(float));
    float* WTs2    = (float*)p;  p += align16((size_t)D * D * sizeof(float));
    float* xs      = (float*)p;  // aliased with hs
    float* hs      = xs;

    // zero the replicated histograms (adjacent -> one memset)
    hipMemsetAsync(cnt8_src, 0, (size_t)2 * NREP * N_NODES * sizeof(int), stream);

    // weight shuffle (both layers, one tiny launch)
    wshuf_kernel<<<dim3(32, 2), D, 0, stream>>>(W1, (float4*)WTs1, W2, (float4*)WTs2);

    // replicated histograms
    deg_kernel<<<EDGE_BLOCKS, 256, 0, stream>>>(src, dst, cnt8_src, cnt8_dst, N_EDGES);

    // hierarchical CSR-offset scan of Σ_r cnt8_dst
    scan_sum_kernel<<<N_SBLK, SCAN_B, 0, stream>>>(cnt8_dst, blkSum, N_NODES);
    scan_off_kernel<<<N_SBLK, SCAN_B, 0, stream>>>(cnt8_dst, blkSum, csr_off, N_NODES, N_SBLK);

    // rs arrays + per-replica cursors + xs = x * rs_out
    prescale_kernel<<<(N_NODES + 7) / 8, 256, 0, stream>>>((const float4*)x, cnt8_src, cnt8_dst,
                                                           csr_off, rs_out, rs_in, cursor8,
                                                           (float4*)xs, N_NODES);

    // CSR column build (low-contention replica cursors)
    scatter_kernel<<<EDGE_BLOCKS, 256, 0, stream>>>(src, dst, cursor8, csr_src, N_EDGES);

    // layer 1 aggregation: msg[n] = sum xs[s]
    gather_kernel<<<(N_NODES + 7) / 8, 256, 0, stream>>>((const float4*)xs, csr_off, csr_src,
                                                         (float4*)msg, N_NODES);

    // layer 1 dense: hs = relu(rs_in * (msg @ W1) + b1) * rs_out
    gemm_kernel<true><<<(N_NODES + GN - 1) / GN, 256, 0, stream>>>((const float4*)msg, rs_in, rs_out,
                                                                   (const float4*)WTs1, b1, hs, N_NODES);

    // layer 2 aggregation: msg[n] = sum hs[s]
    gather_kernel<<<(N_NODES + 7) / 8, 256, 0, stream>>>((const float4*)hs, csr_off, csr_src,
                                                         (float4*)msg, N_NODES);

    // layer 2 dense: out = rs_in * (msg @ W2) + b2
    gemm_kernel<false><<<(N_NODES + GN - 1) / GN, 256, 0, stream>>>((const float4*)msg, rs_in, nullptr,
                                                                    (const float4*)WTs2, b2, out, N_NODES);
}

// Round 7
// 361.023 us; speedup vs baseline: 1.3096x; 1.1420x over previous
//
#include <hip/hip_runtime.h>

#define N_NODES 50000
#define N_EDGES 800000
#define D 128
#define NREP 8      // histogram/cursor replicas
#define SCAN_B 256
#define N_SBLK ((N_NODES + SCAN_B - 1) / SCAN_B)  // 196
#define EDGE_BLOCKS ((N_EDGES + 255) / 256)       // 3125
#define GN 64       // nodes per GEMM block

typedef unsigned short bf16_t;

__device__ inline float bf2f(bf16_t u) {
    union { unsigned int i; float f; } v;
    v.i = ((unsigned int)u) << 16;
    return v.f;
}
__device__ inline bf16_t f2bf(float f) {
    union { float f; unsigned int i; } v;
    v.f = f;
    unsigned int u = v.i;
    unsigned int r = (u + 0x7FFFu + ((u >> 16) & 1u)) >> 16;  // RNE
    return (bf16_t)r;
}
__device__ inline void storeval(float* p, float v) { *p = v; }
__device__ inline void storeval(bf16_t* p, float v) { *p = f2bf(v); }

// ---------------- degree histograms, 8-way replicated ----------------
__global__ void deg_kernel(const int* __restrict__ src, const int* __restrict__ dst,
                           int* __restrict__ cnt8_src, int* __restrict__ cnt8_dst, int nE) {
    int e = blockIdx.x * blockDim.x + threadIdx.x;
    int r = blockIdx.x & (NREP - 1);
    if (e < nE) {
        atomicAdd(&cnt8_src[r * N_NODES + src[e]], 1);
        atomicAdd(&cnt8_dst[r * N_NODES + dst[e]], 1);
    }
}

// ---------------- hierarchical scan, step 1: per-block sums of Σ_r cnt8_dst ----------------
__global__ void scan_sum_kernel(const int* __restrict__ cnt8, int* __restrict__ blkSum, int n) {
    __shared__ int tmp[SCAN_B];
    int t = threadIdx.x;
    int i = blockIdx.x * SCAN_B + t;
    int v = 0;
    if (i < n) {
#pragma unroll
        for (int r = 0; r < NREP; r++) v += cnt8[r * N_NODES + i];
    }
    tmp[t] = v;
    __syncthreads();
    for (int d = 128; d > 0; d >>= 1) {
        if (t < d) tmp[t] += tmp[t + d];
        __syncthreads();
    }
    if (t == 0) blkSum[blockIdx.x] = tmp[0];
}

// ---------------- hierarchical scan, step 2: exclusive offsets ----------------
__global__ void scan_off_kernel(const int* __restrict__ cnt8, const int* __restrict__ blkSum,
                                int* __restrict__ off, int n, int nBlk) {
    __shared__ int bs[SCAN_B];
    __shared__ int tmp[SCAN_B];
    int t = threadIdx.x;
    bs[t] = (t < nBlk) ? blkSum[t] : 0;
    __syncthreads();
    for (int d = 1; d < SCAN_B; d <<= 1) {
        int a = (t >= d) ? bs[t - d] : 0;
        __syncthreads();
        bs[t] += a;
        __syncthreads();
    }
    int base = (blockIdx.x > 0) ? bs[blockIdx.x - 1] : 0;
    int i = blockIdx.x * SCAN_B + t;
    int v = 0;
    if (i < n) {
#pragma unroll
        for (int r = 0; r < NREP; r++) v += cnt8[r * N_NODES + i];
    }
    tmp[t] = v;
    __syncthreads();
    for (int d = 1; d < SCAN_B; d <<= 1) {
        int a = (t >= d) ? tmp[t - d] : 0;
        __syncthreads();
        tmp[t] += a;
        __syncthreads();
    }
    if (i < n) off[i] = base + tmp[t] - v;   // exclusive prefix
    if (i == n - 1) off[n] = base + tmp[t];  // total
}

// ---------------- fused: rs arrays, per-replica cursor init, xs = bf16(x * rs_out) ----------------
__global__ void prescale_kernel(const float4* __restrict__ x, const int* __restrict__ cnt8_src,
                                const int* __restrict__ cnt8_dst, const int* __restrict__ off,
                                float* __restrict__ rs_out, float* __restrict__ rs_in,
                                int* __restrict__ cursor8, ushort4* __restrict__ xs, int nN) {
    int node = blockIdx.x * 8 + (threadIdx.x >> 5);
    int c = threadIdx.x & 31;
    if (node >= nN) return;
    float rs_o = 0.0f;
    if (c == 0) {
        int ssum = 0, dsum = 0;
        int base = off[node];
#pragma unroll
        for (int r = 0; r < NREP; r++) {
            ssum += cnt8_src[r * N_NODES + node];
            int d = cnt8_dst[r * N_NODES + node];
            cursor8[r * N_NODES + node] = base;
            base += d;
            dsum += d;
        }
        rs_o = rsqrtf(fmaxf((float)ssum, 1.0f));
        rs_out[node] = rs_o;
        rs_in[node] = rsqrtf(fmaxf((float)dsum, 1.0f));
    }
    rs_o = __shfl(rs_o, threadIdx.x & 32);  // broadcast from node's lane 0 / 32
    float4 v = x[(size_t)node * 32 + c];
    ushort4 o;
    o.x = f2bf(v.x * rs_o);
    o.y = f2bf(v.y * rs_o);
    o.z = f2bf(v.z * rs_o);
    o.w = f2bf(v.w * rs_o);
    xs[(size_t)node * 32 + c] = o;
}

// ---------------- scatter edges into CSR (replica cursors, same mapping as deg) ----------------
__global__ void scatter_kernel(const int* __restrict__ src, const int* __restrict__ dst,
                               int* __restrict__ cursor8, int* __restrict__ csr_src, int nE) {
    int e = blockIdx.x * blockDim.x + threadIdx.x;
    int r = blockIdx.x & (NREP - 1);
    if (e < nE) {
        int pos = atomicAdd(&cursor8[r * N_NODES + dst[e]], 1);
        csr_src[pos] = src[e];
    }
}

// ---------------- gather aggregation: bf16 rows, fp32 accumulate, 4-way unrolled ----------------
// 32 lanes per node, each lane owns 4 consecutive bf16 (one ushort4 = 8B load; row = 256B)
__global__ void gather_kernel(const ushort4* __restrict__ xin, const int* __restrict__ off,
                              const int* __restrict__ csr_src, float4* __restrict__ msg, int nN) {
    int node = blockIdx.x * 8 + (threadIdx.x >> 5);
    int c = threadIdx.x & 31;
    if (node >= nN) return;
    int beg = off[node], end = off[node + 1];
    float4 a0 = make_float4(0.f, 0.f, 0.f, 0.f);
    float4 a1 = make_float4(0.f, 0.f, 0.f, 0.f);
    float4 a2 = make_float4(0.f, 0.f, 0.f, 0.f);
    float4 a3 = make_float4(0.f, 0.f, 0.f, 0.f);
    int e = beg;
    for (; e + 3 < end; e += 4) {
        int s0 = csr_src[e];
        int s1 = csr_src[e + 1];
        int s2 = csr_src[e + 2];
        int s3 = csr_src[e + 3];
        ushort4 v0 = xin[(size_t)s0 * 32 + c];
        ushort4 v1 = xin[(size_t)s1 * 32 + c];
        ushort4 v2 = xin[(size_t)s2 * 32 + c];
        ushort4 v3 = xin[(size_t)s3 * 32 + c];
        a0.x += bf2f(v0.x); a0.y += bf2f(v0.y); a0.z += bf2f(v0.z); a0.w += bf2f(v0.w);
        a1.x += bf2f(v1.x); a1.y += bf2f(v1.y); a1.z += bf2f(v1.z); a1.w += bf2f(v1.w);
        a2.x += bf2f(v2.x); a2.y += bf2f(v2.y); a2.z += bf2f(v2.z); a2.w += bf2f(v2.w);
        a3.x += bf2f(v3.x); a3.y += bf2f(v3.y); a3.z += bf2f(v3.z); a3.w += bf2f(v3.w);
    }
    for (; e < end; e++) {
        int s0 = csr_src[e];
        ushort4 v0 = xin[(size_t)s0 * 32 + c];
        a0.x += bf2f(v0.x); a0.y += bf2f(v0.y); a0.z += bf2f(v0.z); a0.w += bf2f(v0.w);
    }
    a0.x += a1.x + a2.x + a3.x;
    a0.y += a1.y + a2.y + a3.y;
    a0.z += a1.z + a2.z + a3.z;
    a0.w += a1.w + a2.w + a3.w;
    msg[(size_t)node * 32 + c] = a0;
}

// ---------------- weight shuffle: WTs[k4*128 + col] = {W[4k4+j][col]} ----------------
__global__ void wshuf_kernel(const float* __restrict__ W1, float4* __restrict__ WTs1,
                             const float* __restrict__ W2, float4* __restrict__ WTs2) {
    int col = threadIdx.x;   // 0..127
    int k4 = blockIdx.x;     // 0..31
    const float* W = blockIdx.y ? W2 : W1;
    float4* WTs = blockIdx.y ? WTs2 : WTs1;
    WTs[k4 * D + col] = make_float4(W[(4 * k4 + 0) * D + col], W[(4 * k4 + 1) * D + col],
                                    W[(4 * k4 + 2) * D + col], W[(4 * k4 + 3) * D + col]);
}

// ---------------- dense layer: 64 nodes x 128 cols per block, 8x4 per thread ----------------
// out[node][col] = f( rs_in[node] * (msg[node][:] @ W[:,col]) + bias[col] )
template <bool RELU_OUTSCALE, typename OutT>
__global__ void gemm_kernel(const float4* __restrict__ msg4, const float* __restrict__ rs_in,
                            const float* __restrict__ rs_out, const float4* __restrict__ WTs,
                            const float* __restrict__ bias, OutT* __restrict__ out, int nN) {
    __shared__ float4 sA[GN * 32];  // [node][k4], 32 KB
    int tid = threadIdx.x;          // 0..255
    int n0 = blockIdx.x * GN;
#pragma unroll
    for (int it = 0; it < 8; it++) {
        int idx = it * 256 + tid;
        int node = n0 + (idx >> 5);
        int c = idx & 31;
        sA[idx] = (node < nN) ? msg4[(size_t)node * 32 + c] : make_float4(0.f, 0.f, 0.f, 0.f);
    }
    __syncthreads();
    int tx = tid & 31;   // cols tx, tx+32, tx+64, tx+96
    int ty = tid >> 5;   // nodes ty + 8*i
    float acc[8][4];
#pragma unroll
    for (int i = 0; i < 8; i++)
#pragma unroll
        for (int j = 0; j < 4; j++) acc[i][j] = 0.0f;

    for (int k4 = 0; k4 < 32; k4++) {
        float4 w0 = WTs[k4 * D + tx];
        float4 w1 = WTs[k4 * D + tx + 32];
        float4 w2 = WTs[k4 * D + tx + 64];
        float4 w3 = WTs[k4 * D + tx + 96];
#pragma unroll
        for (int i = 0; i < 8; i++) {
            float4 a = sA[(ty + 8 * i) * 32 + k4];
            acc[i][0] += a.x * w0.x + a.y * w0.y + a.z * w0.z + a.w * w0.w;
            acc[i][1] += a.x * w1.x + a.y * w1.y + a.z * w1.z + a.w * w1.w;
            acc[i][2] += a.x * w2.x + a.y * w2.y + a.z * w2.z + a.w * w2.w;
            acc[i][3] += a.x * w3.x + a.y * w3.y + a.z * w3.z + a.w * w3.w;
        }
    }
    float b0 = bias[tx], b1 = bias[tx + 32], b2 = bias[tx + 64], b3 = bias[tx + 96];
#pragma unroll
    for (int i = 0; i < 8; i++) {
        int node = n0 + ty + 8 * i;
        if (node >= nN) continue;
        float ri = rs_in[node];
        float v0 = acc[i][0] * ri + b0;
        float v1 = acc[i][1] * ri + b1;
        float v2 = acc[i][2] * ri + b2;
        float v3 = acc[i][3] * ri + b3;
        if (RELU_OUTSCALE) {
            float ro = rs_out[node];
            v0 = fmaxf(v0, 0.0f) * ro;
            v1 = fmaxf(v1, 0.0f) * ro;
            v2 = fmaxf(v2, 0.0f) * ro;
            v3 = fmaxf(v3, 0.0f) * ro;
        }
        OutT* o = out + (size_t)node * D;
        storeval(o + tx, v0);
        storeval(o + tx + 32, v1);
        storeval(o + tx + 64, v2);
        storeval(o + tx + 96, v3);
    }
}

static inline size_t align16(size_t x) { return (x + 15) & ~(size_t)15; }

extern "C" void kernel_launch(void* const* d_in, const int* in_sizes, int n_in,
                              void* d_out, int out_size, void* d_ws, size_t ws_size,
                              hipStream_t stream) {
    const float* x   = (const float*)d_in[0];
    const int*   src = (const int*)d_in[1];
    const int*   dst = (const int*)d_in[2];
    const float* W1  = (const float*)d_in[3];
    const float* b1  = (const float*)d_in[4];
    const float* W2  = (const float*)d_in[5];
    const float* b2  = (const float*)d_in[6];
    float* out = (float*)d_out;

    // workspace layout. cnt8/cursor8 (4.8 MB) alias the head of msg (25.6 MB):
    // dead before gather_kernel writes msg. xs (bf16) aliases hs (bf16).
    char* p = (char*)d_ws;
    float* msg      = (float*)p;
    int*   cnt8_src = (int*)p;                        // NREP * N_NODES
    int*   cnt8_dst = cnt8_src + NREP * N_NODES;      // NREP * N_NODES
    int*   cursor8  = cnt8_dst + NREP * N_NODES;      // NREP * N_NODES
    p += align16((size_t)N_NODES * D * sizeof(float));
    int*    csr_off = (int*)p;    p += align16((N_NODES + 1) * sizeof(int));
    int*    blkSum  = (int*)p;    p += align16(N_SBLK * sizeof(int));
    int*    csr_src = (int*)p;    p += align16((size_t)N_EDGES * sizeof(int));
    float*  rs_out  = (float*)p;  p += align16(N_NODES * sizeof(float));
    float*  rs_in   = (float*)p;  p += align16(N_NODES * sizeof(float));
    float*  WTs1    = (float*)p;  p += align16((size_t)D * D * sizeof(float));
    float*  WTs2    = (float*)p;  p += align16((size_t)D * D * sizeof(float));
    bf16_t* xs      = (bf16_t*)p; // aliased with hs (both bf16, 12.8 MB)
    bf16_t* hs      = xs;

    // zero the replicated histograms (adjacent -> one memset)
    hipMemsetAsync(cnt8_src, 0, (size_t)2 * NREP * N_NODES * sizeof(int), stream);

    // weight shuffle (both layers, one tiny launch)
    wshuf_kernel<<<dim3(32, 2), D, 0, stream>>>(W1, (float4*)WTs1, W2, (float4*)WTs2);

    // replicated histograms
    deg_kernel<<<EDGE_BLOCKS, 256, 0, stream>>>(src, dst, cnt8_src, cnt8_dst, N_EDGES);

    // hierarchical CSR-offset scan of Σ_r cnt8_dst
    scan_sum_kernel<<<N_SBLK, SCAN_B, 0, stream>>>(cnt8_dst, blkSum, N_NODES);
    scan_off_kernel<<<N_SBLK, SCAN_B, 0, stream>>>(cnt8_dst, blkSum, csr_off, N_NODES, N_SBLK);

    // rs arrays + per-replica cursors + xs = bf16(x * rs_out)
    prescale_kernel<<<(N_NODES + 7) / 8, 256, 0, stream>>>((const float4*)x, cnt8_src, cnt8_dst,
                                                           csr_off, rs_out, rs_in, cursor8,
                                                           (ushort4*)xs, N_NODES);

    // CSR column build (low-contention replica cursors)
    scatter_kernel<<<EDGE_BLOCKS, 256, 0, stream>>>(src, dst, cursor8, csr_src, N_EDGES);

    // layer 1 aggregation: msg[n] = sum xs[s]  (bf16 rows, fp32 accum)
    gather_kernel<<<(N_NODES + 7) / 8, 256, 0, stream>>>((const ushort4*)xs, csr_off, csr_src,
                                                         (float4*)msg, N_NODES);

    // layer 1 dense: hs = bf16( relu(rs_in * (msg @ W1) + b1) * rs_out )
    gemm_kernel<true, bf16_t><<<(N_NODES + GN - 1) / GN, 256, 0, stream>>>(
        (const float4*)msg, rs_in, rs_out, (const float4*)WTs1, b1, hs, N_NODES);

    // layer 2 aggregation: msg[n] = sum hs[s]
    gather_kernel<<<(N_NODES + 7) / 8, 256, 0, stream>>>((const ushort4*)hs, csr_off, csr_src,
                                                         (float4*)msg, N_NODES);

    // layer 2 dense: out = rs_in * (msg @ W2) + b2  (fp32 output)
    gemm_kernel<false, float><<<(N_NODES + GN - 1) / GN, 256, 0, stream>>>(
        (const float4*)msg, rs_in, nullptr, (const float4*)WTs2, b2, out, N_NODES);
}

// Round 8
// 359.752 us; speedup vs baseline: 1.3142x; 1.0035x over previous
//
#include <hip/hip_runtime.h>

#define N_NODES 50000
#define N_EDGES 800000
#define D 128
#define NREP 8      // histogram/cursor replicas
#define SCAN_B 256
#define N_SBLK ((N_NODES + SCAN_B - 1) / SCAN_B)  // 196
#define EDGE_BLOCKS ((N_EDGES + 255) / 256)       // 3125
#define GN 64       // nodes per GEMM block
#define NSLICE 8    // feature-dim slices (16 cols each) -> per-slice footprint 1.6MB (L2-resident)
#define SLICE_U4 ((size_t)N_NODES * 4)  // ushort4 (bf16) or float4 (msg) elements per slice

typedef unsigned short bf16_t;

__device__ inline float bf2f(bf16_t u) {
    union { unsigned int i; float f; } v;
    v.i = ((unsigned int)u) << 16;
    return v.f;
}
__device__ inline bf16_t f2bf(float f) {
    union { float f; unsigned int i; } v;
    v.f = f;
    unsigned int u = v.i;
    unsigned int r = (u + 0x7FFFu + ((u >> 16) & 1u)) >> 16;  // RNE
    return (bf16_t)r;
}

// ---------------- degree histograms, 8-way replicated ----------------
__global__ void deg_kernel(const int* __restrict__ src, const int* __restrict__ dst,
                           int* __restrict__ cnt8_src, int* __restrict__ cnt8_dst, int nE) {
    int e = blockIdx.x * blockDim.x + threadIdx.x;
    int r = blockIdx.x & (NREP - 1);
    if (e < nE) {
        atomicAdd(&cnt8_src[r * N_NODES + src[e]], 1);
        atomicAdd(&cnt8_dst[r * N_NODES + dst[e]], 1);
    }
}

// ---------------- hierarchical scan, step 1: per-block sums of Σ_r cnt8_dst ----------------
__global__ void scan_sum_kernel(const int* __restrict__ cnt8, int* __restrict__ blkSum, int n) {
    __shared__ int tmp[SCAN_B];
    int t = threadIdx.x;
    int i = blockIdx.x * SCAN_B + t;
    int v = 0;
    if (i < n) {
#pragma unroll
        for (int r = 0; r < NREP; r++) v += cnt8[r * N_NODES + i];
    }
    tmp[t] = v;
    __syncthreads();
    for (int d = 128; d > 0; d >>= 1) {
        if (t < d) tmp[t] += tmp[t + d];
        __syncthreads();
    }
    if (t == 0) blkSum[blockIdx.x] = tmp[0];
}

// ---------------- hierarchical scan, step 2: exclusive offsets ----------------
__global__ void scan_off_kernel(const int* __restrict__ cnt8, const int* __restrict__ blkSum,
                                int* __restrict__ off, int n, int nBlk) {
    __shared__ int bs[SCAN_B];
    __shared__ int tmp[SCAN_B];
    int t = threadIdx.x;
    bs[t] = (t < nBlk) ? blkSum[t] : 0;
    __syncthreads();
    for (int d = 1; d < SCAN_B; d <<= 1) {
        int a = (t >= d) ? bs[t - d] : 0;
        __syncthreads();
        bs[t] += a;
        __syncthreads();
    }
    int base = (blockIdx.x > 0) ? bs[blockIdx.x - 1] : 0;
    int i = blockIdx.x * SCAN_B + t;
    int v = 0;
    if (i < n) {
#pragma unroll
        for (int r = 0; r < NREP; r++) v += cnt8[r * N_NODES + i];
    }
    tmp[t] = v;
    __syncthreads();
    for (int d = 1; d < SCAN_B; d <<= 1) {
        int a = (t >= d) ? tmp[t - d] : 0;
        __syncthreads();
        tmp[t] += a;
        __syncthreads();
    }
    if (i < n) off[i] = base + tmp[t] - v;   // exclusive prefix
    if (i == n - 1) off[n] = base + tmp[t];  // total
}

// ---------------- fused: rs arrays, per-replica cursor init, xs = bf16(x*rs_out), SLICE-MAJOR ----------------
__global__ void prescale_kernel(const float4* __restrict__ x, const int* __restrict__ cnt8_src,
                                const int* __restrict__ cnt8_dst, const int* __restrict__ off,
                                float* __restrict__ rs_out, float* __restrict__ rs_in,
                                int* __restrict__ cursor8, ushort4* __restrict__ xs4, int nN) {
    int node = blockIdx.x * 8 + (threadIdx.x >> 5);
    int c = threadIdx.x & 31;   // float4 chunk = cols 4c..4c+3
    if (node >= nN) return;
    float rs_o = 0.0f;
    if (c == 0) {
        int ssum = 0, dsum = 0;
        int base = off[node];
#pragma unroll
        for (int r = 0; r < NREP; r++) {
            ssum += cnt8_src[r * N_NODES + node];
            int d = cnt8_dst[r * N_NODES + node];
            cursor8[r * N_NODES + node] = base;
            base += d;
            dsum += d;
        }
        rs_o = rsqrtf(fmaxf((float)ssum, 1.0f));
        rs_out[node] = rs_o;
        rs_in[node] = rsqrtf(fmaxf((float)dsum, 1.0f));
    }
    rs_o = __shfl(rs_o, threadIdx.x & 32);  // broadcast from node's lane 0 / 32
    float4 v = x[(size_t)node * 32 + c];
    ushort4 o;
    o.x = f2bf(v.x * rs_o);
    o.y = f2bf(v.y * rs_o);
    o.z = f2bf(v.z * rs_o);
    o.w = f2bf(v.w * rs_o);
    // slice-major: slice = c>>2 (16 cols), sub-chunk = c&3
    xs4[(size_t)(c >> 2) * SLICE_U4 + (size_t)node * 4 + (c & 3)] = o;
}

// ---------------- scatter edges into CSR (replica cursors; ushort column ids) ----------------
__global__ void scatter_kernel(const int* __restrict__ src, const int* __restrict__ dst,
                               int* __restrict__ cursor8, unsigned short* __restrict__ csr_src,
                               int nE) {
    int e = blockIdx.x * blockDim.x + threadIdx.x;
    int r = blockIdx.x & (NREP - 1);
    if (e < nE) {
        int pos = atomicAdd(&cursor8[r * N_NODES + dst[e]], 1);
        csr_src[pos] = (unsigned short)src[e];
    }
}

// ---------------- sliced gather: slice = blockIdx%8 (XCD heuristic), 4 lanes/node ----------------
// Each slice's feature footprint = 1.6MB -> L2-resident on its XCD.
__global__ void gather_kernel(const ushort4* __restrict__ xs4, const int* __restrict__ off,
                              const unsigned short* __restrict__ csr,
                              float4* __restrict__ msg4, int nN) {
    int s = blockIdx.x & (NSLICE - 1);
    int g = blockIdx.x >> 3;
    int node = g * 64 + (threadIdx.x >> 2);
    int lane = threadIdx.x & 3;
    if (node >= nN) return;
    const ushort4* base = xs4 + (size_t)s * SLICE_U4;
    int beg = off[node], end = off[node + 1];
    float4 a0 = make_float4(0.f, 0.f, 0.f, 0.f);
    float4 a1 = make_float4(0.f, 0.f, 0.f, 0.f);
    int e = beg;
    for (; e + 1 < end; e += 2) {
        int s0 = csr[e];
        int s1 = csr[e + 1];
        ushort4 v0 = base[(size_t)s0 * 4 + lane];
        ushort4 v1 = base[(size_t)s1 * 4 + lane];
        a0.x += bf2f(v0.x); a0.y += bf2f(v0.y); a0.z += bf2f(v0.z); a0.w += bf2f(v0.w);
        a1.x += bf2f(v1.x); a1.y += bf2f(v1.y); a1.z += bf2f(v1.z); a1.w += bf2f(v1.w);
    }
    if (e < end) {
        int s0 = csr[e];
        ushort4 v0 = base[(size_t)s0 * 4 + lane];
        a0.x += bf2f(v0.x); a0.y += bf2f(v0.y); a0.z += bf2f(v0.z); a0.w += bf2f(v0.w);
    }
    a0.x += a1.x; a0.y += a1.y; a0.z += a1.z; a0.w += a1.w;
    msg4[(size_t)s * SLICE_U4 + (size_t)node * 4 + lane] = a0;
}

// ---------------- weight shuffle: WTs[k4*128 + col] = {W[4k4+j][col]} ----------------
__global__ void wshuf_kernel(const float* __restrict__ W1, float4* __restrict__ WTs1,
                             const float* __restrict__ W2, float4* __restrict__ WTs2) {
    int col = threadIdx.x;   // 0..127
    int k4 = blockIdx.x;     // 0..31
    const float* W = blockIdx.y ? W2 : W1;
    float4* WTs = blockIdx.y ? WTs2 : WTs1;
    WTs[k4 * D + col] = make_float4(W[(4 * k4 + 0) * D + col], W[(4 * k4 + 1) * D + col],
                                    W[(4 * k4 + 2) * D + col], W[(4 * k4 + 3) * D + col]);
}

// ---------------- dense layer: 64 nodes x 128 cols per block, 8x4 per thread ----------------
// Reads msg in slice-major layout. OUT_SLICED: writes bf16 slice-major (hs);
// else fp32 row-major (final out).
template <bool RELU_OUTSCALE, bool OUT_SLICED>
__global__ void gemm_kernel(const float4* __restrict__ msg4, const float* __restrict__ rs_in,
                            const float* __restrict__ rs_out, const float4* __restrict__ WTs,
                            const float* __restrict__ bias, void* __restrict__ outp, int nN) {
    __shared__ float4 sA[GN * 32];  // [node][k4], 32 KB
    int tid = threadIdx.x;          // 0..255
    int n0 = blockIdx.x * GN;
#pragma unroll
    for (int it = 0; it < 8; it++) {
        int idx = it * 256 + tid;
        int node = n0 + (idx >> 5);
        int c = idx & 31;           // k4 index
        sA[idx] = (node < nN)
            ? msg4[(size_t)(c >> 2) * SLICE_U4 + (size_t)node * 4 + (c & 3)]
            : make_float4(0.f, 0.f, 0.f, 0.f);
    }
    __syncthreads();
    int tx = tid & 31;   // cols tx, tx+32, tx+64, tx+96
    int ty = tid >> 5;   // nodes ty + 8*i
    float acc[8][4];
#pragma unroll
    for (int i = 0; i < 8; i++)
#pragma unroll
        for (int j = 0; j < 4; j++) acc[i][j] = 0.0f;

    for (int k4 = 0; k4 < 32; k4++) {
        float4 w0 = WTs[k4 * D + tx];
        float4 w1 = WTs[k4 * D + tx + 32];
        float4 w2 = WTs[k4 * D + tx + 64];
        float4 w3 = WTs[k4 * D + tx + 96];
#pragma unroll
        for (int i = 0; i < 8; i++) {
            float4 a = sA[(ty + 8 * i) * 32 + k4];
            acc[i][0] += a.x * w0.x + a.y * w0.y + a.z * w0.z + a.w * w0.w;
            acc[i][1] += a.x * w1.x + a.y * w1.y + a.z * w1.z + a.w * w1.w;
            acc[i][2] += a.x * w2.x + a.y * w2.y + a.z * w2.z + a.w * w2.w;
            acc[i][3] += a.x * w3.x + a.y * w3.y + a.z * w3.z + a.w * w3.w;
        }
    }
    float b0 = bias[tx], b1 = bias[tx + 32], b2 = bias[tx + 64], b3 = bias[tx + 96];
#pragma unroll
    for (int i = 0; i < 8; i++) {
        int node = n0 + ty + 8 * i;
        if (node >= nN) continue;
        float ri = rs_in[node];
        float v[4];
        v[0] = acc[i][0] * ri + b0;
        v[1] = acc[i][1] * ri + b1;
        v[2] = acc[i][2] * ri + b2;
        v[3] = acc[i][3] * ri + b3;
        if (RELU_OUTSCALE) {
            float ro = rs_out[node];
#pragma unroll
            for (int j = 0; j < 4; j++) v[j] = fmaxf(v[j], 0.0f) * ro;
        }
        if (OUT_SLICED) {
            bf16_t* o = (bf16_t*)outp;
#pragma unroll
            for (int j = 0; j < 4; j++) {
                int col = tx + 32 * j;
                o[(size_t)(col >> 4) * ((size_t)N_NODES * 16) + (size_t)node * 16 + (col & 15)] =
                    f2bf(v[j]);
            }
        } else {
            float* o = (float*)outp + (size_t)node * D;
            o[tx] = v[0]; o[tx + 32] = v[1]; o[tx + 64] = v[2]; o[tx + 96] = v[3];
        }
    }
}

static inline size_t align16(size_t x) { return (x + 15) & ~(size_t)15; }

extern "C" void kernel_launch(void* const* d_in, const int* in_sizes, int n_in,
                              void* d_out, int out_size, void* d_ws, size_t ws_size,
                              hipStream_t stream) {
    const float* x   = (const float*)d_in[0];
    const int*   src = (const int*)d_in[1];
    const int*   dst = (const int*)d_in[2];
    const float* W1  = (const float*)d_in[3];
    const float* b1  = (const float*)d_in[4];
    const float* W2  = (const float*)d_in[5];
    const float* b2  = (const float*)d_in[6];
    float* out = (float*)d_out;

    // workspace layout. cnt8/cursor8 (4.8 MB) alias the head of msg (25.6 MB):
    // dead before gather_kernel writes msg. xs (sliced bf16) aliases hs.
    char* p = (char*)d_ws;
    float* msg      = (float*)p;                      // sliced: 8 x 200000 float4
    int*   cnt8_src = (int*)p;                        // NREP * N_NODES
    int*   cnt8_dst = cnt8_src + NREP * N_NODES;
    int*   cursor8  = cnt8_dst + NREP * N_NODES;
    p += align16((size_t)N_NODES * D * sizeof(float));
    int*            csr_off = (int*)p;            p += align16((N_NODES + 1) * sizeof(int));
    int*            blkSum  = (int*)p;            p += align16(N_SBLK * sizeof(int));
    unsigned short* csr_src = (unsigned short*)p; p += align16((size_t)N_EDGES * sizeof(unsigned short));
    float*          rs_out  = (float*)p;          p += align16(N_NODES * sizeof(float));
    float*          rs_in   = (float*)p;          p += align16(N_NODES * sizeof(float));
    float*          WTs1    = (float*)p;          p += align16((size_t)D * D * sizeof(float));
    float*          WTs2    = (float*)p;          p += align16((size_t)D * D * sizeof(float));
    bf16_t*         xs      = (bf16_t*)p;         // sliced bf16, aliased with hs (12.8 MB)
    bf16_t*         hs      = xs;

    // zero the replicated histograms (adjacent -> one memset)
    hipMemsetAsync(cnt8_src, 0, (size_t)2 * NREP * N_NODES * sizeof(int), stream);

    // weight shuffle (both layers, one tiny launch)
    wshuf_kernel<<<dim3(32, 2), D, 0, stream>>>(W1, (float4*)WTs1, W2, (float4*)WTs2);

    // replicated histograms
    deg_kernel<<<EDGE_BLOCKS, 256, 0, stream>>>(src, dst, cnt8_src, cnt8_dst, N_EDGES);

    // hierarchical CSR-offset scan of Σ_r cnt8_dst
    scan_sum_kernel<<<N_SBLK, SCAN_B, 0, stream>>>(cnt8_dst, blkSum, N_NODES);
    scan_off_kernel<<<N_SBLK, SCAN_B, 0, stream>>>(cnt8_dst, blkSum, csr_off, N_NODES, N_SBLK);

    // rs arrays + per-replica cursors + xs = bf16(x * rs_out), slice-major
    prescale_kernel<<<(N_NODES + 7) / 8, 256, 0, stream>>>((const float4*)x, cnt8_src, cnt8_dst,
                                                           csr_off, rs_out, rs_in, cursor8,
                                                           (ushort4*)xs, N_NODES);

    // CSR column build (ushort ids)
    scatter_kernel<<<EDGE_BLOCKS, 256, 0, stream>>>(src, dst, cursor8, csr_src, N_EDGES);

    // sliced gathers: 8 slices x 782 node-groups; slice = blockIdx%8 (XCD heuristic)
    int ggrid = NSLICE * ((N_NODES + 63) / 64);

    // layer 1 aggregation: msg = sum xs[s]  (per-slice, L2-resident reads)
    gather_kernel<<<ggrid, 256, 0, stream>>>((const ushort4*)xs, csr_off, csr_src,
                                             (float4*)msg, N_NODES);

    // layer 1 dense: hs = bf16( relu(rs_in * (msg @ W1) + b1) * rs_out ), slice-major
    gemm_kernel<true, true><<<(N_NODES + GN - 1) / GN, 256, 0, stream>>>(
        (const float4*)msg, rs_in, rs_out, (const float4*)WTs1, b1, hs, N_NODES);

    // layer 2 aggregation: msg = sum hs[s]
    gather_kernel<<<ggrid, 256, 0, stream>>>((const ushort4*)hs, csr_off, csr_src,
                                             (float4*)msg, N_NODES);

    // layer 2 dense: out = rs_in * (msg @ W2) + b2  (fp32 row-major)
    gemm_kernel<false, false><<<(N_NODES + GN - 1) / GN, 256, 0, stream>>>(
        (const float4*)msg, rs_in, nullptr, (const float4*)WTs2, b2, out, N_NODES);
}